// Round 1
// baseline (1361.311 us; speedup 1.0000x reference)
//
#include <hip/hip_runtime.h>

typedef _Float16 half2_t __attribute__((ext_vector_type(2)));

#if __has_builtin(__builtin_amdgcn_fdot2)
#define FDOT2(a, b, c) __builtin_amdgcn_fdot2((a), (b), (c), false)
#else
__device__ __forceinline__ float FDOT2(half2_t a, half2_t b, float c) {
    return c + (float)a.x * (float)b.x + (float)a.y * (float)b.y;
}
#endif

namespace {
constexpr int D  = 48;
constexpr int D4 = 24;
constexpr int S2 = D * D4;        // 1152
constexpr int S1 = D * S2;        // 55296
constexpr int SC = D * S1;        // 2654208 elems per channel volume
constexpr int NB = 2;
constexpr int NELEM = NB * 3 * SC;
constexpr int NPAIR_H2 = NB * 3 * SC;   // half2 elements in the pairs buffer
constexpr int NS = NB * D * D * D;      // 221184 spatial lines
}

// ---------------- pack kernels (run once per launch, tiny/BW-bound) ----------

// Wg[l]: (3co, 6ci, 3,3,3, 3k4) fp32 -> pw[((l*3+p)*27 + k123)*9 + co*3 + k4] as half2
__global__ __launch_bounds__(256) void pack_weights(
        const float* __restrict__ Wg, half2_t* __restrict__ pw)
{
    int i = blockIdx.x * 256 + threadIdx.x;
    const int NTOT = 4 * 3 * 27 * 9;          // 2916
    if (i >= NTOT) return;
    int k4 = i % 3; int r = i / 3;
    int co = r % 3; r /= 3;
    int k123 = r % 27; r /= 27;
    int p = r % 3; int l = r / 3;
    int ciA = 2 * p, ciB = 2 * p + 1;
    float a = Wg[((l * 3 + co) * 6 + ciA) * 81 + k123 * 3 + k4];
    float b = Wg[((l * 3 + co) * 6 + ciB) * 81 + k123 * 3 + k4];
    pw[i] = half2_t{(_Float16)a, (_Float16)b};
}

// Build pairs buffer from (f, bnd): pair0=(f0,f1), pair1=(f2,bnd0), pair2=(bnd1,bnd2)
__global__ __launch_bounds__(256) void pack_init(
        const float* __restrict__ f, const float* __restrict__ bnd,
        half2_t* __restrict__ pairs)
{
    int i = blockIdx.x * 256 + threadIdx.x;   // each thread packs 4 consecutive z
    int plane = i / (SC / 4);
    int zz = (i % (SC / 4)) * 4;
    int b = plane / 3, p = plane % 3;
    const float* A; const float* Bc;
    if (p == 0)      { A = f   + (size_t)(b*3 + 0) * SC; Bc = f   + (size_t)(b*3 + 1) * SC; }
    else if (p == 1) { A = f   + (size_t)(b*3 + 2) * SC; Bc = bnd + (size_t)(b*3 + 0) * SC; }
    else             { A = bnd + (size_t)(b*3 + 1) * SC; Bc = bnd + (size_t)(b*3 + 2) * SC; }
    float4 a = *(const float4*)(A + zz);
    float4 c = *(const float4*)(Bc + zz);
    union { float4 f4; half2_t h[4]; } u;
    u.h[0] = half2_t{(_Float16)a.x, (_Float16)c.x};
    u.h[1] = half2_t{(_Float16)a.y, (_Float16)c.y};
    u.h[2] = half2_t{(_Float16)a.z, (_Float16)c.z};
    u.h[3] = half2_t{(_Float16)a.w, (_Float16)c.w};
    *(float4*)(pairs + (size_t)plane * SC + zz) = u.f4;
}

// ---------------- Stage A: gather conv via v_dot2_f32_f16 ---------------------
// j-split: thread = (b,x1,x2,x3, half H). Each thread computes 3 co x 12-wide
// half-line, fp32 accumulation. H is block-uniform (template) so all register
// indices are compile-time.
// Input window per tap: 16 half2 starting at element 8H covers the 12-output
// half plus halo (1 zero-pad at each volume edge of the k4 line).

struct VWin { union { float4 f4[4]; half2_t h[16]; } u; };

template<int H>
__device__ __forceinline__ half2_t hv(const VWin& V, int i)
{
    // i is compile-time after unroll: valid range [0,15]; outside = k4 zero-pad
    return (i < 0 || i > 15) ? half2_t{(_Float16)0, (_Float16)0} : V.u.h[i];
}

template<int H>
__device__ __forceinline__ void convA_body(
        int s, const half2_t* __restrict__ pairs, const half2_t* __restrict__ pw,
        const float* __restrict__ bg, _Float16* __restrict__ dst)
{
    int x3 = s % D; int r = s / D;
    int x2 = r % D; r /= D;
    int x1 = r % D; int b = r / D;

    float acc[3][12];
#pragma unroll
    for (int c = 0; c < 3; ++c) {
        float bb = bg[c];
#pragma unroll
        for (int j = 0; j < 12; ++j) acc[c][j] = bb;
    }

#pragma unroll 1
    for (int p = 0; p < 3; ++p) {
        const half2_t* src = pairs + (size_t)(b*3 + p) * SC;
#pragma unroll 1
        for (int k1 = 0; k1 < 3; ++k1) {
            int z1 = x1 + k1 - 1;
            if ((unsigned)z1 >= (unsigned)D) continue;
            const half2_t* src1 = src + z1 * S1;
#pragma unroll
            for (int k2 = 0; k2 < 3; ++k2) {
                int z2 = x2 + k2 - 1;
                if ((unsigned)z2 >= (unsigned)D) continue;
#pragma unroll
                for (int k3 = 0; k3 < 3; ++k3) {
                    int z3 = x3 + k3 - 1;
                    if ((unsigned)z3 >= (unsigned)D) continue;
                    VWin V;
                    const float4* L = (const float4*)(src1 + z2 * S2 + z3 * D4 + 8*H);
#pragma unroll
                    for (int q = 0; q < 4; ++q) V.u.f4[q] = L[q];
                    const half2_t* w = pw + (size_t)((p * 27 + (k1*9 + k2*3 + k3)) * 9);
#pragma unroll
                    for (int co = 0; co < 3; ++co) {
                        half2_t w0 = w[co*3 + 0];
                        half2_t w1 = w[co*3 + 1];
                        half2_t w2 = w[co*3 + 2];
#pragma unroll
                        for (int j = 0; j < 12; ++j) {
                            // global out j' = 12H + j uses v[j'], v[j'+1], v[j'+2]
                            // v[g] = input[g-1] = V.h[g-1-8H] -> idx = 4H + j + k - 1
                            float a = acc[co][j];
                            a = FDOT2(w0, hv<H>(V, 4*H + j - 1), a);
                            a = FDOT2(w1, hv<H>(V, 4*H + j    ), a);
                            a = FDOT2(w2, hv<H>(V, 4*H + j + 1), a);
                            acc[co][j] = a;
                        }
                    }
                }
            }
        }
    }

    int spos = x1 * S1 + x2 * S2 + x3 * D4 + 12*H;
#pragma unroll
    for (int co = 0; co < 3; ++co) {
        union { float2 f2[3]; _Float16 h[12]; } u;
#pragma unroll
        for (int j = 0; j < 12; ++j) u.h[j] = (_Float16)acc[co][j];
        float2* o2 = (float2*)(dst + (b*3 + co) * (size_t)SC + spos);
#pragma unroll
        for (int q = 0; q < 3; ++q) o2[q] = u.f2[q];
    }
}

__global__ __launch_bounds__(256) void convA(
        const half2_t* __restrict__ pairs, const half2_t* __restrict__ pw,
        const float* __restrict__ bg, _Float16* __restrict__ dst)
{
    int t = blockIdx.x * 256 + threadIdx.x;
    if (t < NS) convA_body<0>(t, pairs, pw, bg, dst);
    else        convA_body<1>(t - NS, pairs, pw, bg, dst);
}

// ---------------- Stage B+C fused, j-split ----------------------------------
// t2 = conv(t1(f16), W1 (3,3,3,1), pad(1,1,1,0)) + b1 (fp32 accum, all 3 ch)
// out = conv(t2, W2 (1,1,1,3)) + b2 + conv(res_f16, Wd 1x1) + bd
// Each thread computes 12 outputs (global j = 12H+n). Needs t2 at global
// j in [12H-1, 12H+12]: local slot m = 0..13, t2l[c][m] <-> global j = 12H+m-1.
// Pad slots (outside [0,24)) stay 0.

template<int H>
__device__ __forceinline__ void convBC_body(
        int s, const _Float16* __restrict__ t1, half2_t* pairs,
        const float* __restrict__ W1, const float* __restrict__ b1,
        const float* __restrict__ W2, const float* __restrict__ b2,
        const float* __restrict__ Wd, const float* __restrict__ bd,
        float* __restrict__ dstF32, int writeF32)
{
    int x3 = s % D; int r = s / D;
    int x2 = r % D; r /= D;
    int x1 = r % D; int b = r / D;

    int spos = x1 * S1 + x2 * S2 + x3 * D4;

    constexpr int M0 = (H == 0) ? 1 : 0;    // first real m slot
    constexpr int M1 = (H == 0) ? 13 : 12;  // last real m slot (inclusive)

    float t2l[3][14];
#pragma unroll
    for (int c = 0; c < 3; ++c) {
        float bb = b1[c];
#pragma unroll
        for (int m = 0; m < 14; ++m)
            t2l[c][m] = (m >= M0 && m <= M1) ? bb : 0.f;
    }

#pragma unroll 1
    for (int ci = 0; ci < 3; ++ci) {
        const _Float16* src = t1 + (b*3 + ci) * (size_t)SC;
#pragma unroll 1
        for (int k1 = 0; k1 < 3; ++k1) {
            int z1 = x1 + k1 - 1;
            if ((unsigned)z1 >= (unsigned)D) continue;
            const _Float16* src1 = src + z1 * S1;
#pragma unroll
            for (int k2 = 0; k2 < 3; ++k2) {
                int z2 = x2 + k2 - 1;
                if ((unsigned)z2 >= (unsigned)D) continue;
#pragma unroll
                for (int k3 = 0; k3 < 3; ++k3) {
                    int z3 = x3 + k3 - 1;
                    if ((unsigned)z3 >= (unsigned)D) continue;
                    // L[i] = t1[8H + i], i = 0..15
                    const float4* L = (const float4*)(src1 + z2 * S2 + z3 * D4 + 8*H);
                    union { float4 f4[2]; half2_t h[8]; } u;
                    u.f4[0] = L[0];
                    u.f4[1] = L[1];
                    int kk = k1*9 + k2*3 + k3;
                    float wA = W1[  0 + ci*27 + kk];
                    float wB = W1[ 81 + ci*27 + kk];
                    float wC = W1[162 + ci*27 + kk];
#pragma unroll
                    for (int m = M0; m <= M1; ++m) {
                        // t1 element index = (12H + m - 1) - 8H = 4H + m - 1
                        int li = 4*H + m - 1;
                        half2_t hh = u.h[li >> 1];
                        float v = (li & 1) ? (float)hh.y : (float)hh.x;
                        t2l[0][m] += wA * v;
                        t2l[1][m] += wB * v;
                        t2l[2][m] += wC * v;
                    }
                }
            }
        }
    }

    // residual source + bnd0 passthrough from pairs (this thread's 12-wide chunk)
    half2_t* p0ptr = pairs + (size_t)(b*3 + 0) * SC + spos + 12*H;
    half2_t* p1ptr = pairs + (size_t)(b*3 + 1) * SC + spos + 12*H;
    half2_t rp0[12], rp1[12];
#pragma unroll
    for (int q = 0; q < 3; ++q) {
        union { float4 f4; half2_t h[4]; } u;
        u.f4 = ((const float4*)p0ptr)[q];
        rp0[4*q+0]=u.h[0]; rp0[4*q+1]=u.h[1]; rp0[4*q+2]=u.h[2]; rp0[4*q+3]=u.h[3];
        u.f4 = ((const float4*)p1ptr)[q];
        rp1[4*q+0]=u.h[0]; rp1[4*q+1]=u.h[1]; rp1[4*q+2]=u.h[2]; rp1[4*q+3]=u.h[3];
    }

    float U[3][3][3];
#pragma unroll
    for (int co = 0; co < 3; ++co)
#pragma unroll
        for (int ci = 0; ci < 3; ++ci)
#pragma unroll
            for (int k = 0; k < 3; ++k)
                U[co][ci][k] = W2[co*9 + ci*3 + k];
    float WD[9];
#pragma unroll
    for (int i = 0; i < 9; ++i) WD[i] = Wd[i];
    float c0 = b2[0] + bd[0], c1 = b2[1] + bd[1], c2 = b2[2] + bd[2];

    float o0[12], o1[12], o2[12];
#pragma unroll
    for (int n = 0; n < 12; ++n) {
        float s0 = c0, s1 = c1, s2 = c2;
#pragma unroll
        for (int ci = 0; ci < 3; ++ci) {
            // global j = 12H + n; needs t2(global j + k - 1) = t2l[ci][n + k]
            float tm = t2l[ci][n + 0];
            float tc = t2l[ci][n + 1];
            float tp = t2l[ci][n + 2];
            s0 += U[0][ci][0]*tm + U[0][ci][1]*tc + U[0][ci][2]*tp;
            s1 += U[1][ci][0]*tm + U[1][ci][1]*tc + U[1][ci][2]*tp;
            s2 += U[2][ci][0]*tm + U[2][ci][1]*tc + U[2][ci][2]*tp;
        }
        float pv0 = (float)rp0[n].x, pv1 = (float)rp0[n].y, pv2 = (float)rp1[n].x;
        s0 += WD[0]*pv0 + WD[1]*pv1 + WD[2]*pv2;
        s1 += WD[3]*pv0 + WD[4]*pv1 + WD[5]*pv2;
        s2 += WD[6]*pv0 + WD[7]*pv1 + WD[8]*pv2;
        o0[n] = s0; o1[n] = s1; o2[n] = s2;
    }

    // vectorized pair stores: plane0 = (o0,o1), plane1 = (o2, bnd0 passthrough)
    {
        union { float4 f4[3]; half2_t h[12]; } u0, u1;
#pragma unroll
        for (int n = 0; n < 12; ++n) {
            u0.h[n] = half2_t{(_Float16)o0[n], (_Float16)o1[n]};
            u1.h[n] = half2_t{(_Float16)o2[n], rp1[n].y};
        }
#pragma unroll
        for (int q = 0; q < 3; ++q) {
            ((float4*)p0ptr)[q] = u0.f4[q];
            ((float4*)p1ptr)[q] = u1.f4[q];
        }
    }

    if (writeF32) {
        float* d0 = dstF32 + (size_t)(b*3 + 0) * SC + spos + 12*H;
        float* d1 = dstF32 + (size_t)(b*3 + 1) * SC + spos + 12*H;
        float* d2 = dstF32 + (size_t)(b*3 + 2) * SC + spos + 12*H;
#pragma unroll
        for (int q = 0; q < 3; ++q) {
            ((float4*)d0)[q] = make_float4(o0[4*q], o0[4*q+1], o0[4*q+2], o0[4*q+3]);
            ((float4*)d1)[q] = make_float4(o1[4*q], o1[4*q+1], o1[4*q+2], o1[4*q+3]);
            ((float4*)d2)[q] = make_float4(o2[4*q], o2[4*q+1], o2[4*q+2], o2[4*q+3]);
        }
    }
}

__global__ __launch_bounds__(256) void convBC(
        const _Float16* __restrict__ t1, half2_t* pairs,
        const float* __restrict__ W1, const float* __restrict__ b1,
        const float* __restrict__ W2, const float* __restrict__ b2,
        const float* __restrict__ Wd, const float* __restrict__ bd,
        float* __restrict__ dstF32, int writeF32)
{
    int t = blockIdx.x * 256 + threadIdx.x;
    if (t < NS) convBC_body<0>(t, t1, pairs, W1, b1, W2, b2, Wd, bd, dstF32, writeF32);
    else        convBC_body<1>(t - NS, t1, pairs, W1, b1, W2, b2, Wd, bd, dstF32, writeF32);
}

extern "C" void kernel_launch(void* const* d_in, const int* in_sizes, int n_in,
                              void* d_out, int out_size, void* d_ws, size_t ws_size,
                              hipStream_t stream)
{
    const float* f   = (const float*)d_in[0];
    const float* bnd = (const float*)d_in[1];
    const float* Wg  = (const float*)d_in[2];
    const float* bg  = (const float*)d_in[3];
    const float* W1  = (const float*)d_in[4];
    const float* b1  = (const float*)d_in[5];
    const float* W2  = (const float*)d_in[6];
    const float* b2  = (const float*)d_in[7];
    const float* Wd  = (const float*)d_in[8];
    const float* bd  = (const float*)d_in[9];

    _Float16* t1h   = (_Float16*)d_ws;                   // 32 MB f16
    half2_t*  pairs = (half2_t*)(t1h + NELEM);           // 64 MB f16 pairs
    half2_t*  pw    = pairs + NPAIR_H2;                  // 11.7 KB packed weights

    pack_weights<<<dim3((2916 + 255) / 256), dim3(256), 0, stream>>>(Wg, pw);
    pack_init<<<dim3(NB * 3 * (SC / 4) / 256), dim3(256), 0, stream>>>(f, bnd, pairs);

    const int grid = 2 * NS / 256;   // 1728 (half 0: blocks 0..863, half 1: 864..1727)
    for (int l = 0; l < 4; ++l) {
        convA<<<dim3(grid), dim3(256), 0, stream>>>(pairs, pw + l * 729, bg + l*3, t1h);
        convBC<<<dim3(grid), dim3(256), 0, stream>>>(
            t1h, pairs, W1 + l*243, b1 + l*3, W2 + l*27, b2 + l*3,
            Wd + l*9, bd + l*3, (float*)d_out, l == 3 ? 1 : 0);
    }
}

// Round 2
// 1071.960 us; speedup vs baseline: 1.2699x; 1.2699x over previous
//
#include <hip/hip_runtime.h>

typedef _Float16 half2_t __attribute__((ext_vector_type(2)));
typedef unsigned int uint32;

#if __has_builtin(__builtin_amdgcn_fdot2)
#define FDOT2(a, b, c) __builtin_amdgcn_fdot2((a), (b), (c), false)
#else
__device__ __forceinline__ float FDOT2(half2_t a, half2_t b, float c) {
    return c + (float)a.x * (float)b.x + (float)a.y * (float)b.y;
}
#endif

__device__ __forceinline__ half2_t h2_from_bits(uint32 b) {
    union { uint32 u; half2_t h; } c; c.u = b; return c.h;
}
__device__ __forceinline__ uint32 bits_from_h2(half2_t h) {
    union { uint32 u; half2_t h; } c; c.h = h; return c.u;
}

namespace {
constexpr int D  = 48;
constexpr int D4 = 24;
constexpr int S2 = D * D4;        // 1152
constexpr int S1 = D * S2;        // 55296
constexpr int SC = D * S1;        // 2654208 elems per channel volume
constexpr int NB = 2;
constexpr int NELEM = NB * 3 * SC;
constexpr int NPAIR_H2 = NB * 3 * SC;   // half2 elements in the pairs buffer
constexpr int NS = NB * D * D * D;      // 221184 spatial lines
}

// ---------------- pack kernels (run once per launch, tiny/BW-bound) ----------

__global__ __launch_bounds__(256) void pack_weights(
        const float* __restrict__ Wg, half2_t* __restrict__ pw)
{
    int i = blockIdx.x * 256 + threadIdx.x;
    const int NTOT = 4 * 3 * 27 * 9;          // 2916
    if (i >= NTOT) return;
    int k4 = i % 3; int r = i / 3;
    int co = r % 3; r /= 3;
    int k123 = r % 27; r /= 27;
    int p = r % 3; int l = r / 3;
    int ciA = 2 * p, ciB = 2 * p + 1;
    float a = Wg[((l * 3 + co) * 6 + ciA) * 81 + k123 * 3 + k4];
    float b = Wg[((l * 3 + co) * 6 + ciB) * 81 + k123 * 3 + k4];
    pw[i] = half2_t{(_Float16)a, (_Float16)b};
}

__global__ __launch_bounds__(256) void pack_init(
        const float* __restrict__ f, const float* __restrict__ bnd,
        half2_t* __restrict__ pairs)
{
    int i = blockIdx.x * 256 + threadIdx.x;   // each thread packs 4 consecutive z
    int plane = i / (SC / 4);
    int zz = (i % (SC / 4)) * 4;
    int b = plane / 3, p = plane % 3;
    const float* A; const float* Bc;
    if (p == 0)      { A = f   + (size_t)(b*3 + 0) * SC; Bc = f   + (size_t)(b*3 + 1) * SC; }
    else if (p == 1) { A = f   + (size_t)(b*3 + 2) * SC; Bc = bnd + (size_t)(b*3 + 0) * SC; }
    else             { A = bnd + (size_t)(b*3 + 1) * SC; Bc = bnd + (size_t)(b*3 + 2) * SC; }
    float4 a = *(const float4*)(A + zz);
    float4 c = *(const float4*)(Bc + zz);
    union { float4 f4; half2_t h[4]; } u;
    u.h[0] = half2_t{(_Float16)a.x, (_Float16)c.x};
    u.h[1] = half2_t{(_Float16)a.y, (_Float16)c.y};
    u.h[2] = half2_t{(_Float16)a.z, (_Float16)c.z};
    u.h[3] = half2_t{(_Float16)a.w, (_Float16)c.w};
    *(float4*)(pairs + (size_t)plane * SC + zz) = u.f4;
}

// ---------------- Stage A: gather conv, lane-interleaved j-split -------------
// Thread t: line = t>>1, H = t&1 (lane pairs share a line).
// Lane computes 3 co x 12 outputs (global j = 12H + j').
// Window W[m] = input[12H - 1 + m], m=0..13:
//   W[0]  = edge: H==1 ? input[11] : 0 (k4 pad)
//   W[1..12] = body input[12H .. 12H+11]  (48 B, float4-aligned)
//   W[13] = edge: H==0 ? input[12] : 0 (k4 pad)
// Single 4B edge load at half2 index 12-H serves both (masked by H).

__global__ __launch_bounds__(256, 4) void convA(
        const half2_t* __restrict__ pairs, const half2_t* __restrict__ pw,
        const float* __restrict__ bg, _Float16* __restrict__ dst)
{
    int t = blockIdx.x * 256 + threadIdx.x;
    int H = t & 1;
    int s = t >> 1;
    int x3 = s % D; int r = s / D;
    int x2 = r % D; r /= D;
    int x1 = r % D; int b = r / D;

    const uint32 maskL = H ? 0xFFFFFFFFu : 0u;   // W[0] live only for H=1
    const uint32 maskR = ~maskL;                  // W[13] live only for H=0
    const int bodyOff = 12 * H;                   // half2 units
    const int edgeOff = 12 - H;                   // half2 units

    float acc[3][12];
#pragma unroll
    for (int c = 0; c < 3; ++c) {
        float bb = bg[c];
#pragma unroll
        for (int j = 0; j < 12; ++j) acc[c][j] = bb;
    }

#pragma unroll 1
    for (int p = 0; p < 3; ++p) {
        const half2_t* src = pairs + (size_t)(b*3 + p) * SC;
#pragma unroll 1
        for (int k1 = 0; k1 < 3; ++k1) {
            int z1 = x1 + k1 - 1;
            if ((unsigned)z1 >= (unsigned)D) continue;
            const half2_t* src1 = src + z1 * S1;
#pragma unroll
            for (int k2 = 0; k2 < 3; ++k2) {
                int z2 = x2 + k2 - 1;
                if ((unsigned)z2 >= (unsigned)D) continue;
#pragma unroll
                for (int k3 = 0; k3 < 3; ++k3) {
                    int z3 = x3 + k3 - 1;
                    if ((unsigned)z3 >= (unsigned)D) continue;
                    const half2_t* lb = src1 + z2 * S2 + z3 * D4;
                    union { float4 f4[3]; half2_t h[12]; } B;
                    const float4* L4 = (const float4*)(lb + bodyOff);
                    B.f4[0] = L4[0]; B.f4[1] = L4[1]; B.f4[2] = L4[2];
                    uint32 ev = *(const uint32*)(lb + edgeOff);

                    half2_t W[14];
                    W[0]  = h2_from_bits(ev & maskL);
#pragma unroll
                    for (int i = 0; i < 12; ++i) W[1 + i] = B.h[i];
                    W[13] = h2_from_bits(ev & maskR);

                    const half2_t* w = pw + (size_t)((p * 27 + (k1*9 + k2*3 + k3)) * 9);
#pragma unroll
                    for (int co = 0; co < 3; ++co) {
                        half2_t w0 = w[co*3 + 0];
                        half2_t w1 = w[co*3 + 1];
                        half2_t w2 = w[co*3 + 2];
#pragma unroll
                        for (int j = 0; j < 12; ++j) {
                            float a = acc[co][j];
                            a = FDOT2(w0, W[j],     a);
                            a = FDOT2(w1, W[j + 1], a);
                            a = FDOT2(w2, W[j + 2], a);
                            acc[co][j] = a;
                        }
                    }
                }
            }
        }
    }

    int spos = x1 * S1 + x2 * S2 + x3 * D4 + 12 * H;
#pragma unroll
    for (int co = 0; co < 3; ++co) {
        union { float2 f2[3]; _Float16 h[12]; } u;
#pragma unroll
        for (int j = 0; j < 12; ++j) u.h[j] = (_Float16)acc[co][j];
        float2* o2 = (float2*)(dst + (b*3 + co) * (size_t)SC + spos);
#pragma unroll
        for (int q = 0; q < 3; ++q) o2[q] = u.f2[q];
    }
}

// ---------------- Stage B+C fused, lane-interleaved j-split ------------------
// t2 slot m = 0..13 <-> global j = 12H + m - 1 (slot 0 zero for H=0, slot 13
// zero for H=1 -- those are stage-C k4 pads). Stage B (k4 kernel = 1) needs
// t1[12H-1 .. 12H+12]: 12-value body (24 B) + one live edge at f16 idx 12-H.

__global__ __launch_bounds__(256, 3) void convBC(
        const _Float16* __restrict__ t1, half2_t* pairs,
        const float* __restrict__ W1, const float* __restrict__ b1,
        const float* __restrict__ W2, const float* __restrict__ b2,
        const float* __restrict__ Wd, const float* __restrict__ bd,
        float* __restrict__ dstF32, int writeF32)
{
    int t = blockIdx.x * 256 + threadIdx.x;
    int H = t & 1;
    int s = t >> 1;
    int x3 = s % D; int r = s / D;
    int x2 = r % D; r /= D;
    int x1 = r % D; int b = r / D;
    const bool isH1 = (H != 0);

    int spos = x1 * S1 + x2 * S2 + x3 * D4;
    const int bodyOff = 12 * H;       // f16 units
    const int edgeOff = 12 - H;       // f16 units

    float t2l[3][14];
#pragma unroll
    for (int c = 0; c < 3; ++c) {
        float bb = b1[c];
        t2l[c][0]  = isH1 ? bb : 0.f;
        t2l[c][13] = isH1 ? 0.f : bb;
#pragma unroll
        for (int m = 1; m < 13; ++m) t2l[c][m] = bb;
    }

#pragma unroll 1
    for (int ci = 0; ci < 3; ++ci) {
        const _Float16* src = t1 + (b*3 + ci) * (size_t)SC;
#pragma unroll 1
        for (int k1 = 0; k1 < 3; ++k1) {
            int z1 = x1 + k1 - 1;
            if ((unsigned)z1 >= (unsigned)D) continue;
            const _Float16* src1 = src + z1 * S1;
#pragma unroll
            for (int k2 = 0; k2 < 3; ++k2) {
                int z2 = x2 + k2 - 1;
                if ((unsigned)z2 >= (unsigned)D) continue;
#pragma unroll
                for (int k3 = 0; k3 < 3; ++k3) {
                    int z3 = x3 + k3 - 1;
                    if ((unsigned)z3 >= (unsigned)D) continue;
                    const _Float16* lb = src1 + z2 * S2 + z3 * D4;
                    union { float2 f2[3]; half2_t h[6]; } Bd;
                    const float2* L2 = (const float2*)(lb + bodyOff);
                    Bd.f2[0] = L2[0]; Bd.f2[1] = L2[1]; Bd.f2[2] = L2[2];
                    _Float16 eh = lb[edgeOff];
                    float ef = (float)eh;

                    float v[14];
                    v[0]  = isH1 ? ef : 0.f;
                    v[13] = isH1 ? 0.f : ef;
#pragma unroll
                    for (int i = 0; i < 6; ++i) {
                        v[1 + 2*i] = (float)Bd.h[i].x;
                        v[2 + 2*i] = (float)Bd.h[i].y;
                    }
                    int kk = k1*9 + k2*3 + k3;
                    float wA = W1[  0 + ci*27 + kk];
                    float wB = W1[ 81 + ci*27 + kk];
                    float wC = W1[162 + ci*27 + kk];
#pragma unroll
                    for (int m = 0; m < 14; ++m) {
                        t2l[0][m] += wA * v[m];
                        t2l[1][m] += wB * v[m];
                        t2l[2][m] += wC * v[m];
                    }
                }
            }
        }
    }

    // residual source + bnd0 passthrough from pairs (this lane's 12-wide chunk)
    half2_t* p0ptr = pairs + (size_t)(b*3 + 0) * SC + spos + 12*H;
    half2_t* p1ptr = pairs + (size_t)(b*3 + 1) * SC + spos + 12*H;
    half2_t rp0[12], rp1[12];
#pragma unroll
    for (int q = 0; q < 3; ++q) {
        union { float4 f4; half2_t h[4]; } u;
        u.f4 = ((const float4*)p0ptr)[q];
        rp0[4*q+0]=u.h[0]; rp0[4*q+1]=u.h[1]; rp0[4*q+2]=u.h[2]; rp0[4*q+3]=u.h[3];
        u.f4 = ((const float4*)p1ptr)[q];
        rp1[4*q+0]=u.h[0]; rp1[4*q+1]=u.h[1]; rp1[4*q+2]=u.h[2]; rp1[4*q+3]=u.h[3];
    }

    float U[3][3][3];
#pragma unroll
    for (int co = 0; co < 3; ++co)
#pragma unroll
        for (int ci = 0; ci < 3; ++ci)
#pragma unroll
            for (int k = 0; k < 3; ++k)
                U[co][ci][k] = W2[co*9 + ci*3 + k];
    float WD[9];
#pragma unroll
    for (int i = 0; i < 9; ++i) WD[i] = Wd[i];
    float c0 = b2[0] + bd[0], c1 = b2[1] + bd[1], c2 = b2[2] + bd[2];

    float o0[12], o1[12], o2[12];
#pragma unroll
    for (int n = 0; n < 12; ++n) {
        float s0 = c0, s1 = c1, s2 = c2;
#pragma unroll
        for (int ci = 0; ci < 3; ++ci) {
            float tm = t2l[ci][n + 0];
            float tc = t2l[ci][n + 1];
            float tp = t2l[ci][n + 2];
            s0 += U[0][ci][0]*tm + U[0][ci][1]*tc + U[0][ci][2]*tp;
            s1 += U[1][ci][0]*tm + U[1][ci][1]*tc + U[1][ci][2]*tp;
            s2 += U[2][ci][0]*tm + U[2][ci][1]*tc + U[2][ci][2]*tp;
        }
        float pv0 = (float)rp0[n].x, pv1 = (float)rp0[n].y, pv2 = (float)rp1[n].x;
        s0 += WD[0]*pv0 + WD[1]*pv1 + WD[2]*pv2;
        s1 += WD[3]*pv0 + WD[4]*pv1 + WD[5]*pv2;
        s2 += WD[6]*pv0 + WD[7]*pv1 + WD[8]*pv2;
        o0[n] = s0; o1[n] = s1; o2[n] = s2;
    }

    // vectorized pair stores: plane0 = (o0,o1), plane1 = (o2, bnd0 passthrough)
    {
        union { float4 f4[3]; half2_t h[12]; } u0, u1;
#pragma unroll
        for (int n = 0; n < 12; ++n) {
            u0.h[n] = half2_t{(_Float16)o0[n], (_Float16)o1[n]};
            u1.h[n] = half2_t{(_Float16)o2[n], rp1[n].y};
        }
#pragma unroll
        for (int q = 0; q < 3; ++q) {
            ((float4*)p0ptr)[q] = u0.f4[q];
            ((float4*)p1ptr)[q] = u1.f4[q];
        }
    }

    if (writeF32) {
        float* d0 = dstF32 + (size_t)(b*3 + 0) * SC + spos + 12*H;
        float* d1 = dstF32 + (size_t)(b*3 + 1) * SC + spos + 12*H;
        float* d2 = dstF32 + (size_t)(b*3 + 2) * SC + spos + 12*H;
#pragma unroll
        for (int q = 0; q < 3; ++q) {
            ((float4*)d0)[q] = make_float4(o0[4*q], o0[4*q+1], o0[4*q+2], o0[4*q+3]);
            ((float4*)d1)[q] = make_float4(o1[4*q], o1[4*q+1], o1[4*q+2], o1[4*q+3]);
            ((float4*)d2)[q] = make_float4(o2[4*q], o2[4*q+1], o2[4*q+2], o2[4*q+3]);
        }
    }
}

extern "C" void kernel_launch(void* const* d_in, const int* in_sizes, int n_in,
                              void* d_out, int out_size, void* d_ws, size_t ws_size,
                              hipStream_t stream)
{
    const float* f   = (const float*)d_in[0];
    const float* bnd = (const float*)d_in[1];
    const float* Wg  = (const float*)d_in[2];
    const float* bg  = (const float*)d_in[3];
    const float* W1  = (const float*)d_in[4];
    const float* b1  = (const float*)d_in[5];
    const float* W2  = (const float*)d_in[6];
    const float* b2  = (const float*)d_in[7];
    const float* Wd  = (const float*)d_in[8];
    const float* bd  = (const float*)d_in[9];

    _Float16* t1h   = (_Float16*)d_ws;                   // 32 MB f16
    half2_t*  pairs = (half2_t*)(t1h + NELEM);           // 64 MB f16 pairs
    half2_t*  pw    = pairs + NPAIR_H2;                  // 11.7 KB packed weights

    pack_weights<<<dim3((2916 + 255) / 256), dim3(256), 0, stream>>>(Wg, pw);
    pack_init<<<dim3(NB * 3 * (SC / 4) / 256), dim3(256), 0, stream>>>(f, bnd, pairs);

    const int grid = 2 * NS / 256;   // 1728 blocks; lane pairs share a line
    for (int l = 0; l < 4; ++l) {
        convA<<<dim3(grid), dim3(256), 0, stream>>>(pairs, pw + l * 729, bg + l*3, t1h);
        convBC<<<dim3(grid), dim3(256), 0, stream>>>(
            t1h, pairs, W1 + l*243, b1 + l*3, W2 + l*27, b2 + l*3,
            Wd + l*9, bd + l*3, (float*)d_out, l == 3 ? 1 : 0);
    }
}